// Round 6
// baseline (433.984 us; speedup 1.0000x reference)
//
#include <hip/hip_runtime.h>
#include <hip/hip_fp16.h>
#include <string.h>

namespace {
constexpr int kN = 50000;
constexpr int kD = 256;
constexpr int kPos = 32;
constexpr int kNeg = 20;
constexpr float kEps = 1e-15f;

// ---------- software fp8 e4m3fn <-> f32 via the f16 bit-correspondence ----------
// e4m3 value = f16(bits: s<<15 | e<<10.. | m<<7) * 2^8   (exact, incl. subnormals)

__device__ __forceinline__ uint enc1(float x) {
    const __half hh = __float2half(x * 0.00390625f);  // x * 2^-8, HW RNE
    unsigned short t;
    memcpy(&t, &hh, 2);
    const uint s = ((uint)t >> 8) & 0x80u;
    uint mag = (uint)t & 0x7fffu;
    mag = mag + 0x3fu + ((mag >> 7) & 1u);  // RNE 10-bit -> 3-bit mantissa
    uint u = mag >> 7;
    if (u > 0x7eu) u = 0x7eu;  // saturate below NaN encoding (never hit for N(0,1))
    return s | u;
}

__device__ __forceinline__ float dec_h(uint h) {  // h = f16 bits in low 16
    __half hh;
    const unsigned short t = (unsigned short)h;
    memcpy(&hh, &t, 2);
    return __half2float(hh);
}

// decode 4 fp8 bytes packed in u, fma against own_s[0..3] (own pre-scaled by 2^8)
__device__ __forceinline__ void dq4(uint u, const float* o, float& d) {
    const float v0 = dec_h(((u << 8) & 0x8000u) | ((u << 7) & 0x3f80u));
    const float v1 = dec_h((u & 0x8000u) | ((u >> 1) & 0x3f80u));
    const float v2 = dec_h(((u >> 8) & 0x8000u) | ((u >> 9) & 0x3f80u));
    const float v3 = dec_h(((u >> 16) & 0x8000u) | ((u >> 17) & 0x3f80u));
    d = fmaf(v0, o[0], d);
    d = fmaf(v1, o[1], d);
    d = fmaf(v2, o[2], d);
    d = fmaf(v3, o[3], d);
}

// ---------- fp32 -> fp8 table conversion; also zeroes the accumulators ----------
// 8 elems/thread: read 32 B, write 8 B. Grid covers kN*kD exactly.
__global__ __launch_bounds__(256) void convert_fp8(const float* __restrict__ emb,
                                                   uint* __restrict__ tbl,
                                                   float* __restrict__ acc) {
    if (blockIdx.x == 0 && threadIdx.x < 4) acc[threadIdx.x] = 0.f;
    const size_t i = ((size_t)blockIdx.x * 256 + threadIdx.x) * 8;
    const float4* src = reinterpret_cast<const float4*>(emb + i);
    const float4 a = src[0];
    const float4 b = src[1];
    uint2 o;
    o.x = enc1(a.x) | (enc1(a.y) << 8) | (enc1(a.z) << 16) | (enc1(a.w) << 24);
    o.y = enc1(b.x) | (enc1(b.y) << 8) | (enc1(b.z) << 16) | (enc1(b.w) << 24);
    reinterpret_cast<uint2*>(tbl)[i / 8] = o;
}

// One wave per row; wave = 4 groups x 16 lanes, one neighbor per group per
// iteration. fp8 row = 256 B; lane t loads one uint4 (elems 16t..16t+15), so
// each gather instruction covers 4 rows x 256 B = 16 full cache lines.
__global__ __launch_bounds__(256) void row_loss_fp8(
    const float* __restrict__ emb,
    const uchar* __restrict__ tblb,
    const int* __restrict__ nbr,
    const int* __restrict__ nbrm,
    const int* __restrict__ neg,
    const int* __restrict__ rmask,
    float* __restrict__ acc) {
    __shared__ float s_num[4];
    __shared__ float s_den[4];
    const int wave = threadIdx.x >> 6;
    const int lane = threadIdx.x & 63;
    const int n = blockIdx.x * 4 + wave;
    const int g = lane >> 4;
    const int t = lane & 15;

    const int rm = rmask[n];
    float num = 0.f;

    if (rm) {
        // own row fp32 (exact), elems 16t..16t+15, pre-scaled by 2^8 to fold the
        // fp8->f16 decode scale.
        const float4* erow = reinterpret_cast<const float4*>(emb + (size_t)n * kD);
        float own[16];
#pragma unroll
        for (int j = 0; j < 4; ++j) {
            const float4 f = erow[4 * t + j];
            own[4 * j + 0] = f.x * 256.f;
            own[4 * j + 1] = f.y * 256.f;
            own[4 * j + 2] = f.z * 256.f;
            own[4 * j + 3] = f.w * 256.f;
        }

        const int* nrow = nbr + (size_t)n * kPos;
        const int* mrow = nbrm + (size_t)n * kPos;
        const int* grow = neg + (size_t)n * kNeg;

        float pos_sum = 0.f, neg_sum = 0.f, cnt = 0.f;

#pragma unroll
        for (int it = 0; it < kPos / 4; ++it) {
            const int idx = nrow[it * 4 + g];
            const int m = mrow[it * 4 + g];
            cnt += (float)m;
            if (m) {  // group-uniform: masked slot skips the gather entirely
                const uint4 u =
                    *reinterpret_cast<const uint4*>(tblb + (size_t)idx * 256 + t * 16);
                float d = 0.f;
                dq4(u.x, own + 0, d);
                dq4(u.y, own + 4, d);
                dq4(u.z, own + 8, d);
                dq4(u.w, own + 12, d);
                d += __shfl_xor(d, 8);
                d += __shfl_xor(d, 4);
                d += __shfl_xor(d, 2);
                d += __shfl_xor(d, 1);
                const float s = 1.f / (1.f + __expf(-d));
                pos_sum += -__logf(s + kEps);
            }
        }

#pragma unroll
        for (int it = 0; it < kNeg / 4; ++it) {
            const int idx = grow[it * 4 + g];
            const uint4 u =
                *reinterpret_cast<const uint4*>(tblb + (size_t)idx * 256 + t * 16);
            float d = 0.f;
            dq4(u.x, own + 0, d);
            dq4(u.y, own + 4, d);
            dq4(u.z, own + 8, d);
            dq4(u.w, own + 12, d);
            d += __shfl_xor(d, 8);
            d += __shfl_xor(d, 4);
            d += __shfl_xor(d, 2);
            d += __shfl_xor(d, 1);
            const float s = 1.f / (1.f + __expf(-d));
            neg_sum += -__logf(1.f - s + kEps);
        }

        // combine the 4 groups (each group's 16 lanes hold identical values)
        pos_sum += __shfl_xor(pos_sum, 16);
        pos_sum += __shfl_xor(pos_sum, 32);
        neg_sum += __shfl_xor(neg_sum, 16);
        neg_sum += __shfl_xor(neg_sum, 32);
        cnt += __shfl_xor(cnt, 16);
        cnt += __shfl_xor(cnt, 32);

        if (cnt > 0.f) num = pos_sum / cnt + neg_sum / (float)kNeg;
        // cnt==0 -> NaN row in reference -> replaced by 0 -> contributes 0
    }

    if (lane == 0) {
        s_num[wave] = num;
        s_den[wave] = (float)rm;
    }
    __syncthreads();
    if (threadIdx.x == 0) {
        atomicAdd(&acc[0], s_num[0] + s_num[1] + s_num[2] + s_num[3]);
        atomicAdd(&acc[1], s_den[0] + s_den[1] + s_den[2] + s_den[3]);
    }
}

// ---------- fp32 direct fallback (only if d_ws can't hold the 12.8 MB table) ----------
__global__ __launch_bounds__(256) void row_loss_f32(
    const float* __restrict__ emb,
    const int* __restrict__ nbr,
    const int* __restrict__ nbrm,
    const int* __restrict__ neg,
    const int* __restrict__ rmask,
    float* __restrict__ acc) {
    __shared__ float s_num[4];
    __shared__ float s_den[4];
    const int wave = threadIdx.x >> 6;
    const int lane = threadIdx.x & 63;
    const int n = blockIdx.x * 4 + wave;
    const int g = lane >> 4;
    const int t = lane & 15;

    const int rm = rmask[n];
    float num = 0.f;

    if (rm) {
        const float4* erow = reinterpret_cast<const float4*>(emb + (size_t)n * kD);
        float4 own4[4];
#pragma unroll
        for (int j = 0; j < 4; ++j) own4[j] = erow[j * 16 + t];

        const int* nrow = nbr + (size_t)n * kPos;
        const int* mrow = nbrm + (size_t)n * kPos;
        const int* grow = neg + (size_t)n * kNeg;

        float pos_sum = 0.f, neg_sum = 0.f, cnt = 0.f;

#pragma unroll
        for (int it = 0; it < kPos / 4; ++it) {
            const int idx = nrow[it * 4 + g];
            const int m = mrow[it * 4 + g];
            cnt += (float)m;
            if (m) {
                const float4* brow = reinterpret_cast<const float4*>(emb + (size_t)idx * kD);
                float d = 0.f;
#pragma unroll
                for (int j = 0; j < 4; ++j) {
                    const float4 b = brow[j * 16 + t];
                    const float4 a = own4[j];
                    d += a.x * b.x + a.y * b.y + a.z * b.z + a.w * b.w;
                }
                d += __shfl_xor(d, 8);
                d += __shfl_xor(d, 4);
                d += __shfl_xor(d, 2);
                d += __shfl_xor(d, 1);
                const float s = 1.f / (1.f + __expf(-d));
                pos_sum += -__logf(s + kEps);
            }
        }

#pragma unroll
        for (int it = 0; it < kNeg / 4; ++it) {
            const int idx = grow[it * 4 + g];
            const float4* brow = reinterpret_cast<const float4*>(emb + (size_t)idx * kD);
            float d = 0.f;
#pragma unroll
            for (int j = 0; j < 4; ++j) {
                const float4 b = brow[j * 16 + t];
                const float4 a = own4[j];
                d += a.x * b.x + a.y * b.y + a.z * b.z + a.w * b.w;
            }
            d += __shfl_xor(d, 8);
            d += __shfl_xor(d, 4);
            d += __shfl_xor(d, 2);
            d += __shfl_xor(d, 1);
            const float s = 1.f / (1.f + __expf(-d));
            neg_sum += -__logf(1.f - s + kEps);
        }

        pos_sum += __shfl_xor(pos_sum, 16);
        pos_sum += __shfl_xor(pos_sum, 32);
        neg_sum += __shfl_xor(neg_sum, 16);
        neg_sum += __shfl_xor(neg_sum, 32);
        cnt += __shfl_xor(cnt, 16);
        cnt += __shfl_xor(cnt, 32);

        if (cnt > 0.f) num = pos_sum / cnt + neg_sum / (float)kNeg;
    }

    if (lane == 0) {
        s_num[wave] = num;
        s_den[wave] = (float)rm;
    }
    __syncthreads();
    if (threadIdx.x == 0) {
        atomicAdd(&acc[0], s_num[0] + s_num[1] + s_num[2] + s_num[3]);
        atomicAdd(&acc[1], s_den[0] + s_den[1] + s_den[2] + s_den[3]);
    }
}

__global__ void finalize_kernel(const float* __restrict__ acc, float* __restrict__ out) {
    out[0] = acc[0] / acc[1];
}
}  // namespace

extern "C" void kernel_launch(void* const* d_in, const int* in_sizes, int n_in,
                              void* d_out, int out_size, void* d_ws, size_t ws_size,
                              hipStream_t stream) {
    const float* emb = (const float*)d_in[0];
    const int* nbr = (const int*)d_in[1];
    const int* nbrm = (const int*)d_in[2];
    const int* neg = (const int*)d_in[3];
    const int* rmask = (const int*)d_in[4];
    float* acc = (float*)d_ws;

    const size_t tbl_bytes = (size_t)kN * kD;  // 1 B/elem = 12.8 MB
    if (ws_size >= 256 + tbl_bytes) {
        uint* tbl = (uint*)((char*)d_ws + 256);
        convert_fp8<<<kN * kD / 8 / 256, 256, 0, stream>>>(emb, tbl, acc);
        row_loss_fp8<<<kN / 4, 256, 0, stream>>>(emb, (const uchar*)tbl, nbr, nbrm, neg,
                                                 rmask, acc);
    } else {
        hipMemsetAsync(acc, 0, 2 * sizeof(float), stream);
        row_loss_f32<<<kN / 4, 256, 0, stream>>>(emb, nbr, nbrm, neg, rmask, acc);
    }
    finalize_kernel<<<1, 1, 0, stream>>>(acc, (float*)d_out);
}

// Round 7
// 204.866 us; speedup vs baseline: 2.1184x; 2.1184x over previous
//
#include <hip/hip_runtime.h>
#include <hip/hip_fp16.h>
#include <string.h>

namespace {
constexpr int kN = 50000;
constexpr int kD = 256;
constexpr int kPos = 32;
constexpr int kNeg = 20;
constexpr float kEps = 1e-15f;
constexpr int kSlots = kPos / 4 + kNeg / 4;  // 13 per 16-lane group

// ---------- software fp8 e4m3fn <-> f32 via the f16 bit-correspondence ----------
// e4m3 value = f16(bits: s<<15 | e<<10.. | m<<7) * 2^8  (exact, incl. subnormals)
__device__ __forceinline__ uint enc1(float x) {
    const __half hh = __float2half(x * 0.00390625f);  // x * 2^-8, HW RNE
    unsigned short t;
    memcpy(&t, &hh, 2);
    const uint s = ((uint)t >> 8) & 0x80u;
    uint mag = (uint)t & 0x7fffu;
    mag = mag + 0x3fu + ((mag >> 7) & 1u);  // RNE 10->3 bit mantissa
    uint u = mag >> 7;
    if (u > 0x7eu) u = 0x7eu;
    return s | u;
}

__device__ __forceinline__ float dec_h(uint h) {
    __half hh;
    const unsigned short t = (unsigned short)h;
    memcpy(&hh, &t, 2);
    return __half2float(hh);
}

__device__ __forceinline__ void dq4(uint u, const float* o, float& d) {
    const float v0 = dec_h(((u << 8) & 0x8000u) | ((u << 7) & 0x3f80u));
    const float v1 = dec_h((u & 0x8000u) | ((u >> 1) & 0x3f80u));
    const float v2 = dec_h(((u >> 8) & 0x8000u) | ((u >> 9) & 0x3f80u));
    const float v3 = dec_h(((u >> 16) & 0x8000u) | ((u >> 17) & 0x3f80u));
    d = fmaf(v0, o[0], d);
    d = fmaf(v1, o[1], d);
    d = fmaf(v2, o[2], d);
    d = fmaf(v3, o[3], d);
}

// ---------- fp32 -> fp8 table; 8 elems/thread ----------
__global__ __launch_bounds__(256) void convert_fp8(const float* __restrict__ emb,
                                                   uint* __restrict__ tbl) {
    const size_t i = ((size_t)blockIdx.x * 256 + threadIdx.x) * 8;
    const float4* src = reinterpret_cast<const float4*>(emb + i);
    const float4 a = src[0];
    const float4 b = src[1];
    uint2 o;
    o.x = enc1(a.x) | (enc1(a.y) << 8) | (enc1(a.z) << 16) | (enc1(a.w) << 24);
    o.y = enc1(b.x) | (enc1(b.y) << 8) | (enc1(b.z) << 16) | (enc1(b.w) << 24);
    reinterpret_cast<uint2*>(tbl)[i / 8] = o;
}

// ---------- active-row compaction (order irrelevant) ----------
__global__ __launch_bounds__(256) void compact_kernel(const int* __restrict__ rmask,
                                                      int* __restrict__ list,
                                                      float* __restrict__ acc) {
    const int n = blockIdx.x * 256 + threadIdx.x;
    if (n < kN && rmask[n]) {
        const int p = atomicAdd(reinterpret_cast<unsigned*>(&acc[2]), 1u);
        list[p] = n;
    }
}

// One wave per ACTIVE row (via compacted list); wave = 4 groups x 16 lanes,
// one neighbor per group per slot, 13 slots, fully branch-free: every slot
// gathers (fp8 row 256 B, lane t loads one uint4 = elems 16t..16t+15; a wave
// instruction covers 4 rows x 256 B contiguous). Pos mask applied as weight.
__global__ __launch_bounds__(256) void row_loss_fp8(
    const float* __restrict__ emb,
    const uchar* __restrict__ tblb,
    const int* __restrict__ nbr,
    const int* __restrict__ nbrm,
    const int* __restrict__ neg,
    const int* __restrict__ list,
    float* __restrict__ acc) {
    __shared__ float s_num[4];
    const int wave = threadIdx.x >> 6;
    const int lane = threadIdx.x & 63;
    const int g = lane >> 4;
    const int t = lane & 15;

    const int cnt_active = reinterpret_cast<const int*>(acc)[2];
    const int i = blockIdx.x * 4 + wave;
    float num = 0.f;

    if (i < cnt_active) {  // wave-uniform
        const int n = list[i];

        // own row fp32 (exact), elems 16t..16t+15, pre-scaled by 2^8 to fold
        // the fp8->f16 decode scale.
        const float4* erow = reinterpret_cast<const float4*>(emb + (size_t)n * kD);
        float own[16];
#pragma unroll
        for (int j = 0; j < 4; ++j) {
            const float4 f = erow[4 * t + j];
            own[4 * j + 0] = f.x * 256.f;
            own[4 * j + 1] = f.y * 256.f;
            own[4 * j + 2] = f.z * 256.f;
            own[4 * j + 3] = f.w * 256.f;
        }

        const int* nrow = nbr + (size_t)n * kPos;
        const int* mrow = nbrm + (size_t)n * kPos;
        const int* grow = neg + (size_t)n * kNeg;

        // preload all indices + weights: keeps the slot loop branch-free and
        // lets the compiler software-pipeline the gathers.
        int idx[kSlots];
        float w[kPos / 4];
        float cnt = 0.f;
#pragma unroll
        for (int s = 0; s < kPos / 4; ++s) {
            idx[s] = nrow[s * 4 + g];
            const float mf = (float)mrow[s * 4 + g];
            w[s] = mf;
            cnt += mf;
        }
#pragma unroll
        for (int s = 0; s < kNeg / 4; ++s) idx[kPos / 4 + s] = grow[s * 4 + g];

        float pos_sum = 0.f, neg_sum = 0.f;
#pragma unroll
        for (int s = 0; s < kSlots; ++s) {
            const uint4 u =
                *reinterpret_cast<const uint4*>(tblb + (size_t)idx[s] * 256 + t * 16);
            float d = 0.f;
            dq4(u.x, own + 0, d);
            dq4(u.y, own + 4, d);
            dq4(u.z, own + 8, d);
            dq4(u.w, own + 12, d);
            d += __shfl_xor(d, 8);
            d += __shfl_xor(d, 4);
            d += __shfl_xor(d, 2);
            d += __shfl_xor(d, 1);
            const float sg = 1.f / (1.f + __expf(-d));
            if (s < kPos / 4) {  // compile-time branch (fully unrolled)
                pos_sum += -__logf(sg + kEps) * w[s];
            } else {
                neg_sum += -__logf(1.f - sg + kEps);
            }
        }

        // combine the 4 groups (each group's 16 lanes hold identical values)
        pos_sum += __shfl_xor(pos_sum, 16);
        pos_sum += __shfl_xor(pos_sum, 32);
        neg_sum += __shfl_xor(neg_sum, 16);
        neg_sum += __shfl_xor(neg_sum, 32);
        cnt += __shfl_xor(cnt, 16);
        cnt += __shfl_xor(cnt, 32);

        if (cnt > 0.f) num = pos_sum / cnt + neg_sum / (float)kNeg;
        // cnt==0 -> NaN row in reference -> replaced by 0 -> contributes 0
    }

    if (lane == 0) s_num[wave] = num;
    __syncthreads();
    if (threadIdx.x == 0) {
        const float v = s_num[0] + s_num[1] + s_num[2] + s_num[3];
        if (v != 0.f) atomicAdd(&acc[0], v);
    }
}

__global__ void finalize_kernel(const float* __restrict__ acc, float* __restrict__ out) {
    out[0] = acc[0] / (float)reinterpret_cast<const int*>(acc)[2];
}

// ---------- fp32 direct fallback (only if d_ws too small; branch-free R1 form) ----------
__global__ __launch_bounds__(256) void row_loss_f32(
    const float* __restrict__ emb,
    const int* __restrict__ nbr,
    const int* __restrict__ nbrm,
    const int* __restrict__ neg,
    const int* __restrict__ rmask,
    float* __restrict__ acc) {
    __shared__ float s_num[4];
    __shared__ float s_den[4];
    const int wave = threadIdx.x >> 6;
    const int lane = threadIdx.x & 63;
    const int n = blockIdx.x * 4 + wave;
    const int g = lane >> 4;
    const int t = lane & 15;

    const float4* erow = reinterpret_cast<const float4*>(emb + (size_t)n * kD);
    float4 own4[4];
#pragma unroll
    for (int j = 0; j < 4; ++j) own4[j] = erow[j * 16 + t];

    const int* nrow = nbr + (size_t)n * kPos;
    const int* mrow = nbrm + (size_t)n * kPos;
    const int* grow = neg + (size_t)n * kNeg;

    float pos_sum = 0.f, neg_sum = 0.f, cnt = 0.f;
#pragma unroll
    for (int it = 0; it < kPos / 4; ++it) {
        const int idx = nrow[it * 4 + g];
        const float mf = (float)mrow[it * 4 + g];
        cnt += mf;
        const float4* brow = reinterpret_cast<const float4*>(emb + (size_t)idx * kD);
        float d = 0.f;
#pragma unroll
        for (int j = 0; j < 4; ++j) {
            const float4 b = brow[j * 16 + t];
            const float4 a = own4[j];
            d += a.x * b.x + a.y * b.y + a.z * b.z + a.w * b.w;
        }
        d += __shfl_xor(d, 8);
        d += __shfl_xor(d, 4);
        d += __shfl_xor(d, 2);
        d += __shfl_xor(d, 1);
        const float s = 1.f / (1.f + __expf(-d));
        pos_sum += -__logf(s + kEps) * mf;
    }
#pragma unroll
    for (int it = 0; it < kNeg / 4; ++it) {
        const int idx = grow[it * 4 + g];
        const float4* brow = reinterpret_cast<const float4*>(emb + (size_t)idx * kD);
        float d = 0.f;
#pragma unroll
        for (int j = 0; j < 4; ++j) {
            const float4 b = brow[j * 16 + t];
            const float4 a = own4[j];
            d += a.x * b.x + a.y * b.y + a.z * b.z + a.w * b.w;
        }
        d += __shfl_xor(d, 8);
        d += __shfl_xor(d, 4);
        d += __shfl_xor(d, 2);
        d += __shfl_xor(d, 1);
        const float s = 1.f / (1.f + __expf(-d));
        neg_sum += -__logf(1.f - s + kEps);
    }

    pos_sum += __shfl_xor(pos_sum, 16);
    pos_sum += __shfl_xor(pos_sum, 32);
    neg_sum += __shfl_xor(neg_sum, 16);
    neg_sum += __shfl_xor(neg_sum, 32);
    cnt += __shfl_xor(cnt, 16);
    cnt += __shfl_xor(cnt, 32);

    float num = 0.f;
    if (cnt > 0.f) num = pos_sum / cnt + neg_sum / (float)kNeg;
    const float rmf = (float)rmask[n];

    if (lane == 0) {
        s_num[wave] = num * rmf;
        s_den[wave] = rmf;
    }
    __syncthreads();
    if (threadIdx.x == 0) {
        atomicAdd(&acc[0], s_num[0] + s_num[1] + s_num[2] + s_num[3]);
        atomicAdd(&acc[1], s_den[0] + s_den[1] + s_den[2] + s_den[3]);
    }
}

__global__ void finalize_f32(const float* __restrict__ acc, float* __restrict__ out) {
    out[0] = acc[0] / acc[1];
}
}  // namespace

extern "C" void kernel_launch(void* const* d_in, const int* in_sizes, int n_in,
                              void* d_out, int out_size, void* d_ws, size_t ws_size,
                              hipStream_t stream) {
    const float* emb = (const float*)d_in[0];
    const int* nbr = (const int*)d_in[1];
    const int* nbrm = (const int*)d_in[2];
    const int* neg = (const int*)d_in[3];
    const int* rmask = (const int*)d_in[4];
    float* acc = (float*)d_ws;  // [0]=num, [1]=den, [2]=active count

    const size_t tbl_bytes = (size_t)kN * kD;  // 12.8 MB
    const size_t list_bytes = (size_t)kN * sizeof(int);
    if (ws_size >= 256 + tbl_bytes + list_bytes) {
        uint* tbl = (uint*)((char*)d_ws + 256);
        int* list = (int*)((char*)d_ws + 256 + tbl_bytes);
        hipMemsetAsync(acc, 0, 4 * sizeof(float), stream);
        compact_kernel<<<(kN + 255) / 256, 256, 0, stream>>>(rmask, list, acc);
        convert_fp8<<<kN * kD / 8 / 256, 256, 0, stream>>>(emb, tbl);
        row_loss_fp8<<<(kN + 3) / 4, 256, 0, stream>>>(emb, (const uchar*)tbl, nbr, nbrm,
                                                       neg, list, acc);
        finalize_kernel<<<1, 1, 0, stream>>>(acc, (float*)d_out);
    } else {
        hipMemsetAsync(acc, 0, 2 * sizeof(float), stream);
        row_loss_f32<<<kN / 4, 256, 0, stream>>>(emb, nbr, nbrm, neg, rmask, acc);
        finalize_f32<<<1, 1, 0, stream>>>(acc, (float*)d_out);
    }
}